// Round 2
// baseline (431.231 us; speedup 1.0000x reference)
//
#include <hip/hip_runtime.h>
#include <math.h>

// Problem constants (fixed by reference)
#define B_TREES 64
#define N_NODES 65536
#define D 1024          // D_MEM == D_HID == 1024
#define D4 (D/4)        // 256 float4 per row

#define CHUNK 64                    // nodes per block (one boundary max: min seg len >= 341)
#define SUB 8                       // nodes staged in LDS at a time (8 rows * 4KB = 32KB)
#define NSUB (CHUNK/SUB)            // 8 sub-tiles per chunk
#define NCHUNK (N_NODES/CHUNK)      // 1024 blocks
#define NSLOT (2*NCHUNK)            // 2 slots per chunk (<=2 segments per chunk)
#define VZ 8                        // h-chunks in v_part

// ---- in-block offsets: wave 0 loads lens (int32/int64 autodetect), shfl-scan ----
// Writes soff[0..64] (exclusive prefix in soff[b], total at soff[64]).
__device__ __forceinline__ void block_offsets(const int* __restrict__ lens32,
                                              int* __restrict__ soff,
                                              int tid, int lane) {
    if ((tid >> 6) == 0) {
        long long x32 = (long long)lens32[lane];
        long long tot = x32;
        #pragma unroll
        for (int o = 32; o > 0; o >>= 1) tot += __shfl_xor(tot, o, 64);
        int len = (tot == (long long)N_NODES) ? (int)x32
                                              : (int)(((const long long*)lens32)[lane]);
        int scan = len;
        #pragma unroll
        for (int o = 1; o < 64; o <<= 1) {
            int y = __shfl_up(scan, o, 64);
            if (lane >= o) scan += y;
        }
        soff[lane + 1] = scan;
        if (lane == 0) soff[0] = 0;
    }
}

// ---------------- Kernel 1: v_part[z][b][m] = sum_{h in chunk z} ds[b][h]*W[h][m] ----
// grid: (4 m-tiles of 256, 16 b-groups of 4, 8 h-chunks of 128); block 256. Plain stores.
__global__ __launch_bounds__(256) void v_kernel(const float* __restrict__ ds,
                                                const float* __restrict__ W,
                                                float* __restrict__ v_part) {
    const int m  = blockIdx.x * 256 + threadIdx.x;
    const int b0 = blockIdx.y * 4;
    const int z  = blockIdx.z;
    const int h0 = z * 128;
    float acc[4] = {0.f, 0.f, 0.f, 0.f};
    for (int h = h0; h < h0 + 128; ++h) {
        float wv = W[h * D + m];                 // coalesced across threads
        #pragma unroll
        for (int j = 0; j < 4; ++j)
            acc[j] += ds[(b0 + j) * D + h] * wv; // wave-uniform -> scalar loads
    }
    #pragma unroll
    for (int j = 0; j < 4; ++j)
        v_part[((size_t)(z * B_TREES + b0 + j)) * D + m] = acc[j];
}

// ---------------- Kernel 2: fused scores + per-chunk online softmax + partial ctx
// One block per 64-node chunk. Register-prefetched LDS staging (async-split):
// next sub-tile's global loads issue right after the staging barrier and retire
// under the dots+accum compute of the current sub-tile.
__global__ __launch_bounds__(256, 4) void fused_kernel(
    const float4* __restrict__ mb, const float4* __restrict__ v_part,
    const int* __restrict__ lens32,
    float* __restrict__ m_arr, float* __restrict__ z_arr,
    int* __restrict__ seg_arr, float4* __restrict__ vec)
{
    __shared__ float4 smb[SUB * D4];   // 32 KB staging tile
    __shared__ float  ssc[SUB];        // sub-tile scores
    __shared__ int    soff[B_TREES + 1];

    const int tid  = threadIdx.x;
    const int wave = tid >> 6;
    const int lane = tid & 63;
    const int c    = blockIdx.x;
    const int n0   = c * CHUNK;

    // prologue prefetch of sub-tile 0 (independent of the offsets scan)
    float4 pf[SUB];
    #pragma unroll
    for (int k = 0; k < SUB; ++k)
        pf[k] = mb[(size_t)(n0 + k) * D4 + tid];

    block_offsets(lens32, soff, tid, lane);
    __syncthreads();

    // segment geometry (redundant in all threads; soff reads are LDS broadcasts)
    int lo = 0, hi = B_TREES - 1;
    while (lo < hi) { int mid = (lo + hi + 1) >> 1; if (soff[mid] <= n0) lo = mid; else hi = mid - 1; }
    const int sa   = lo;
    const int nxt  = soff[sa + 1];
    const int cutg = (nxt < n0 + CHUNK) ? nxt : 0x7fffffff;
    const bool two = (cutg != 0x7fffffff);

    // online-softmax state per sub-segment, replicated identically in all threads
    float  m0 = -INFINITY, z0 = 0.f, m1 = -INFINITY, z1 = 0.f;
    float4 a0 = make_float4(0.f, 0.f, 0.f, 0.f);
    float4 a1 = make_float4(0.f, 0.f, 0.f, 0.f);

    // hoisted v row (sum of VZ partials) for this wave's lane slice
    float4 vr0, vr1, vr2, vr3;
    int vcur = -1;

    for (int st = 0; st < NSUB; ++st) {
        const int nb = n0 + st * SUB;

        // ---- commit prefetched sub-tile to LDS
        #pragma unroll
        for (int k = 0; k < SUB; ++k)
            smb[k * D4 + tid] = pf[k];
        __syncthreads();

        // ---- issue next sub-tile's loads; they retire under compute below
        if (st + 1 < NSUB) {
            const int nb2 = nb + SUB;
            #pragma unroll
            for (int k = 0; k < SUB; ++k)
                pf[k] = mb[(size_t)(nb2 + k) * D4 + tid];
        }

        // ---- dots: wave handles nodes k = wave*2 + {0,1}
        #pragma unroll
        for (int q = 0; q < 2; ++q) {
            const int k  = wave * 2 + q;
            const int sg = (nb + k < cutg) ? sa : sa + 1;   // wave-uniform
            if (sg != vcur) {                               // <=2 times per block
                vcur = sg;
                vr0 = make_float4(0.f,0.f,0.f,0.f); vr1 = vr0; vr2 = vr0; vr3 = vr0;
                #pragma unroll
                for (int z = 0; z < VZ; ++z) {
                    const float4* vp = v_part + (size_t)(z * B_TREES + sg) * D4;
                    float4 t;
                    t = vp[  0 + lane]; vr0.x+=t.x; vr0.y+=t.y; vr0.z+=t.z; vr0.w+=t.w;
                    t = vp[ 64 + lane]; vr1.x+=t.x; vr1.y+=t.y; vr1.z+=t.z; vr1.w+=t.w;
                    t = vp[128 + lane]; vr2.x+=t.x; vr2.y+=t.y; vr2.z+=t.z; vr2.w+=t.w;
                    t = vp[192 + lane]; vr3.x+=t.x; vr3.y+=t.y; vr3.z+=t.z; vr3.w+=t.w;
                }
            }
            const float4 b0v = smb[k * D4 +   0 + lane];
            const float4 b1v = smb[k * D4 +  64 + lane];
            const float4 b2v = smb[k * D4 + 128 + lane];
            const float4 b3v = smb[k * D4 + 192 + lane];
            float acc = b0v.x*vr0.x + b0v.y*vr0.y + b0v.z*vr0.z + b0v.w*vr0.w;
            acc      += b1v.x*vr1.x + b1v.y*vr1.y + b1v.z*vr1.z + b1v.w*vr1.w;
            acc      += b2v.x*vr2.x + b2v.y*vr2.y + b2v.z*vr2.z + b2v.w*vr2.w;
            acc      += b3v.x*vr3.x + b3v.y*vr3.y + b3v.z*vr3.z + b3v.w*vr3.w;
            #pragma unroll
            for (int o = 32; o > 0; o >>= 1) acc += __shfl_down(acc, o, 64);
            if (lane == 0) ssc[k] = acc;
        }
        __syncthreads();

        // ---- online-softmax weighted accumulate (all branches block-uniform)
        #pragma unroll
        for (int k = 0; k < SUB; ++k) {
            const float  s    = ssc[k];              // LDS broadcast
            const float4 arow = smb[k * D4 + tid];   // contiguous b128, conflict-free
            if (nb + k < cutg) {
                if (s > m0) {
                    const float sc = __expf(m0 - s); // exp(-inf)=0 handles init
                    z0 *= sc; a0.x *= sc; a0.y *= sc; a0.z *= sc; a0.w *= sc;
                    m0 = s;
                }
                const float w = __expf(s - m0);
                z0 += w;
                a0.x += w * arow.x; a0.y += w * arow.y; a0.z += w * arow.z; a0.w += w * arow.w;
            } else {
                if (s > m1) {
                    const float sc = __expf(m1 - s);
                    z1 *= sc; a1.x *= sc; a1.y *= sc; a1.z *= sc; a1.w *= sc;
                    m1 = s;
                }
                const float w = __expf(s - m1);
                z1 += w;
                a1.x += w * arow.x; a1.y += w * arow.y; a1.z += w * arow.z; a1.w += w * arow.w;
            }
        }
        __syncthreads();   // protect smb/ssc before next staging pass
    }

    // ---- emit chunk partials (every slot's segid is written every launch)
    const int slot0 = 2 * c, slot1 = 2 * c + 1;
    vec[(size_t)slot0 * D4 + tid] = a0;
    if (tid == 0) { m_arr[slot0] = m0; z_arr[slot0] = z0; seg_arr[slot0] = sa; }
    if (two) {
        vec[(size_t)slot1 * D4 + tid] = a1;
        if (tid == 0) { m_arr[slot1] = m1; z_arr[slot1] = z1; seg_arr[slot1] = sa + 1; }
    } else if (tid == 0) {
        seg_arr[slot1] = -1;
    }
}

// ---------------- Kernel 3: combine chunk partials per segment ----------------
// out[b] = (sum_slots e^{m_slot - m_seg} vec_slot) / (sum_slots e^{m_slot - m_seg} z_slot)
__global__ __launch_bounds__(256) void combine_kernel(
    const int* __restrict__ lens32, const float* __restrict__ m_arr,
    const float* __restrict__ z_arr, const int* __restrict__ seg_arr,
    const float4* __restrict__ vec, float4* __restrict__ out)
{
    __shared__ int soff[B_TREES + 1];
    const int t = threadIdx.x, lane = t & 63;
    block_offsets(lens32, soff, t, lane);
    __syncthreads();

    const int b  = blockIdx.x;
    const int s0 = soff[b], s1 = soff[b + 1];
    const int c0 = s0 / CHUNK, c1 = (s1 - 1) / CHUNK;   // chunks intersecting segment b

    float mseg = -INFINITY;
    for (int cc = c0; cc <= c1; ++cc) {
        #pragma unroll
        for (int j = 0; j < 2; ++j) {
            const int sl = 2 * cc + j;
            if (seg_arr[sl] == b) mseg = fmaxf(mseg, m_arr[sl]);
        }
    }
    float zseg = 0.f;
    float4 acc = make_float4(0.f, 0.f, 0.f, 0.f);
    for (int cc = c0; cc <= c1; ++cc) {
        #pragma unroll
        for (int j = 0; j < 2; ++j) {
            const int sl = 2 * cc + j;
            if (seg_arr[sl] == b) {                     // block-uniform
                const float sc = __expf(m_arr[sl] - mseg);
                zseg += sc * z_arr[sl];
                const float4 vv = vec[(size_t)sl * D4 + t];
                acc.x += sc * vv.x; acc.y += sc * vv.y;
                acc.z += sc * vv.z; acc.w += sc * vv.w;
            }
        }
    }
    const float inv = 1.f / zseg;
    acc.x *= inv; acc.y *= inv; acc.z *= inv; acc.w *= inv;
    out[(size_t)b * D4 + t] = acc;
}

extern "C" void kernel_launch(void* const* d_in, const int* in_sizes, int n_in,
                              void* d_out, int out_size, void* d_ws, size_t ws_size,
                              hipStream_t stream) {
    const float* mb   = (const float*)d_in[0];       // [N, 1024]
    const float* ds   = (const float*)d_in[1];       // [64, 1024]
    const float* W    = (const float*)d_in[2];       // [1024, 1024]
    const int*   lens = (const int*)d_in[3];         // [64] int32 (or int64 — autodetected)
    float*       out  = (float*)d_out;               // [64, 1024]

    // workspace layout (~10.3 MB), all 16B-aligned:
    //   v_part [8][64][1024] f32 (2 MB) | m (8 KB) | z (8 KB) | seg (8 KB) | vec (8 MB)
    char*  ws      = (char*)d_ws;
    float* v_part  = (float*)ws;
    float* m_arr   = (float*)(ws + (size_t)VZ * B_TREES * D * 4);
    float* z_arr   = m_arr + NSLOT;
    int*   seg_arr = (int*)(z_arr + NSLOT);
    float* vec     = (float*)((char*)(seg_arr + NSLOT));

    {
        dim3 grid(4, 16, VZ);
        v_kernel<<<grid, 256, 0, stream>>>(ds, W, v_part);
    }

    fused_kernel<<<NCHUNK, 256, 0, stream>>>(
        (const float4*)mb, (const float4*)v_part, lens,
        m_arr, z_arr, seg_arr, (float4*)vec);

    combine_kernel<<<B_TREES, 256, 0, stream>>>(
        lens, m_arr, z_arr, seg_arr, (const float4*)vec, (float4*)out);
}

// Round 3
// 399.462 us; speedup vs baseline: 1.0795x; 1.0795x over previous
//
#include <hip/hip_runtime.h>
#include <math.h>

// Problem constants (fixed by reference)
#define B_TREES 64
#define N_NODES 65536
#define D 1024          // D_MEM == D_HID == 1024
#define D4 (D/4)        // 256 float4 per row

#define CHUNK 64                    // nodes per block (one boundary max: min seg len >= 341)
#define SUB 8                       // nodes per register tile (8 float4/thread = 32 VGPR)
#define NSUB (CHUNK/SUB)            // 8 sub-tiles per chunk
#define NCHUNK (N_NODES/CHUNK)      // 1024 blocks
#define NSLOT (2*NCHUNK)            // 2 slots per chunk (<=2 segments per chunk)
#define VZ 8                        // h-chunks in v_part

// ---- in-block offsets: wave 0 loads lens (int32/int64 autodetect), shfl-scan ----
__device__ __forceinline__ void block_offsets(const int* __restrict__ lens32,
                                              int* __restrict__ soff,
                                              int tid, int lane) {
    if ((tid >> 6) == 0) {
        long long x32 = (long long)lens32[lane];
        long long tot = x32;
        #pragma unroll
        for (int o = 32; o > 0; o >>= 1) tot += __shfl_xor(tot, o, 64);
        int len = (tot == (long long)N_NODES) ? (int)x32
                                              : (int)(((const long long*)lens32)[lane]);
        int scan = len;
        #pragma unroll
        for (int o = 1; o < 64; o <<= 1) {
            int y = __shfl_up(scan, o, 64);
            if (lane >= o) scan += y;
        }
        soff[lane + 1] = scan;
        if (lane == 0) soff[0] = 0;
    }
}

// ---------------- Kernel 1: v_part[z][b][m] = sum_{h in chunk z} ds[b][h]*W[h][m] ----
__global__ __launch_bounds__(256) void v_kernel(const float* __restrict__ ds,
                                                const float* __restrict__ W,
                                                float* __restrict__ v_part) {
    const int m  = blockIdx.x * 256 + threadIdx.x;
    const int b0 = blockIdx.y * 4;
    const int z  = blockIdx.z;
    const int h0 = z * 128;
    float acc[4] = {0.f, 0.f, 0.f, 0.f};
    for (int h = h0; h < h0 + 128; ++h) {
        float wv = W[h * D + m];                 // coalesced across threads
        #pragma unroll
        for (int j = 0; j < 4; ++j)
            acc[j] += ds[(b0 + j) * D + h] * wv; // wave-uniform -> scalar loads
    }
    #pragma unroll
    for (int j = 0; j < 4; ++j)
        v_part[((size_t)(z * B_TREES + b0 + j)) * D + m] = acc[j];
}

// ---------------- Kernel 2: register-resident fused scores+softmax+partial-ctx ----
// Thread t owns d-slice [4t..4t+3]. Per 8-node sub-tile: 8 coalesced float4 loads
// stay in registers; per-thread partial dots vs the thread's v-slice; 256->1 score
// reduce via 6x shfl_xor + tiny double-buffered LDS (1 barrier/sub-tile); weighted
// accumulation reads the row from registers. No 32KB staging tile, no b128 LDS reads.
__global__ __launch_bounds__(256, 4) void fused_kernel(
    const float4* __restrict__ mb, const float4* __restrict__ v_part,
    const int* __restrict__ lens32,
    float* __restrict__ m_arr, float* __restrict__ z_arr,
    int* __restrict__ seg_arr, float4* __restrict__ vec)
{
    __shared__ float red[2][4][SUB];     // [parity][wave][node] partial sums
    __shared__ int   soff[B_TREES + 1];

    const int tid  = threadIdx.x;
    const int wave = tid >> 6;
    const int lane = tid & 63;
    const int c    = blockIdx.x;
    const int n0   = c * CHUNK;

    block_offsets(lens32, soff, tid, lane);
    __syncthreads();

    // segment geometry (block-uniform; soff reads are LDS broadcasts)
    int lo = 0, hi = B_TREES - 1;
    while (lo < hi) { int mid = (lo + hi + 1) >> 1; if (soff[mid] <= n0) lo = mid; else hi = mid - 1; }
    const int sa   = lo;
    const int nxt  = soff[sa + 1];
    const int cutg = (nxt < n0 + CHUNK) ? nxt : 0x7fffffff;
    const bool two = (cutg != 0x7fffffff);

    // this thread's v-slice for segment sa (and sa+1 if the cut is inside the chunk)
    float4 vA = make_float4(0.f, 0.f, 0.f, 0.f);
    #pragma unroll
    for (int z = 0; z < VZ; ++z) {
        const float4 t4 = v_part[(size_t)(z * B_TREES + sa) * D4 + tid];
        vA.x += t4.x; vA.y += t4.y; vA.z += t4.z; vA.w += t4.w;
    }
    float4 vB = vA;
    if (two) {
        vB = make_float4(0.f, 0.f, 0.f, 0.f);
        #pragma unroll
        for (int z = 0; z < VZ; ++z) {
            const float4 t4 = v_part[(size_t)(z * B_TREES + sa + 1) * D4 + tid];
            vB.x += t4.x; vB.y += t4.y; vB.z += t4.z; vB.w += t4.w;
        }
    }

    // online-softmax state (replicated identically in all threads)
    float  m0 = -INFINITY, z0 = 0.f, m1 = -INFINITY, z1 = 0.f;
    float4 a0 = make_float4(0.f, 0.f, 0.f, 0.f);
    float4 a1 = make_float4(0.f, 0.f, 0.f, 0.f);

    for (int st = 0; st < NSUB; ++st) {
        const int nb = n0 + st * SUB;

        // ---- 8 independent coalesced loads; rows live in registers
        float4 m4[SUB];
        #pragma unroll
        for (int k = 0; k < SUB; ++k)
            m4[k] = mb[(size_t)(nb + k) * D4 + tid];

        // ---- per-thread partial dots (block-uniform branch on the cut)
        float p[SUB];
        if (nb + SUB <= cutg) {
            #pragma unroll
            for (int k = 0; k < SUB; ++k)
                p[k] = m4[k].x*vA.x + m4[k].y*vA.y + m4[k].z*vA.z + m4[k].w*vA.w;
        } else if (nb >= cutg) {
            #pragma unroll
            for (int k = 0; k < SUB; ++k)
                p[k] = m4[k].x*vB.x + m4[k].y*vB.y + m4[k].z*vB.z + m4[k].w*vB.w;
        } else {
            #pragma unroll
            for (int k = 0; k < SUB; ++k) {
                const float4 vk = (nb + k < cutg) ? vA : vB;
                p[k] = m4[k].x*vk.x + m4[k].y*vk.y + m4[k].z*vk.z + m4[k].w*vk.w;
            }
        }

        // ---- wave butterfly reduce (all lanes end with the wave sum)
        #pragma unroll
        for (int k = 0; k < SUB; ++k) {
            #pragma unroll
            for (int o = 32; o > 0; o >>= 1)
                p[k] += __shfl_xor(p[k], o, 64);
        }

        // ---- cross-wave combine via tiny double-buffered LDS; 1 barrier/sub-tile
        const int par = st & 1;
        if (lane == 0) {
            #pragma unroll
            for (int k = 0; k < SUB; ++k) red[par][wave][k] = p[k];
        }
        __syncthreads();
        float s[SUB];
        #pragma unroll
        for (int k = 0; k < SUB; ++k)
            s[k] = red[par][0][k] + red[par][1][k] + red[par][2][k] + red[par][3][k];

        // ---- online-softmax weighted accumulate from registers (block-uniform)
        #pragma unroll
        for (int k = 0; k < SUB; ++k) {
            const float sc_ = s[k];
            if (nb + k < cutg) {
                if (sc_ > m0) {
                    const float r = __expf(m0 - sc_);   // exp(-inf)=0 handles init
                    z0 *= r; a0.x *= r; a0.y *= r; a0.z *= r; a0.w *= r;
                    m0 = sc_;
                }
                const float w = __expf(sc_ - m0);
                z0 += w;
                a0.x += w * m4[k].x; a0.y += w * m4[k].y;
                a0.z += w * m4[k].z; a0.w += w * m4[k].w;
            } else {
                if (sc_ > m1) {
                    const float r = __expf(m1 - sc_);
                    z1 *= r; a1.x *= r; a1.y *= r; a1.z *= r; a1.w *= r;
                    m1 = sc_;
                }
                const float w = __expf(sc_ - m1);
                z1 += w;
                a1.x += w * m4[k].x; a1.y += w * m4[k].y;
                a1.z += w * m4[k].z; a1.w += w * m4[k].w;
            }
        }
        // no trailing barrier: parity double-buffer separates st's reads of
        // red[par] from the next write to red[par] (at st+2) by the st+1 barrier
    }

    // ---- emit chunk partials (every slot's segid is written every launch)
    const int slot0 = 2 * c, slot1 = 2 * c + 1;
    vec[(size_t)slot0 * D4 + tid] = a0;
    if (tid == 0) { m_arr[slot0] = m0; z_arr[slot0] = z0; seg_arr[slot0] = sa; }
    if (two) {
        vec[(size_t)slot1 * D4 + tid] = a1;
        if (tid == 0) { m_arr[slot1] = m1; z_arr[slot1] = z1; seg_arr[slot1] = sa + 1; }
    } else if (tid == 0) {
        seg_arr[slot1] = -1;
    }
}

// ---------------- Kernel 3: combine chunk partials per segment ----------------
__global__ __launch_bounds__(256) void combine_kernel(
    const int* __restrict__ lens32, const float* __restrict__ m_arr,
    const float* __restrict__ z_arr, const int* __restrict__ seg_arr,
    const float4* __restrict__ vec, float4* __restrict__ out)
{
    __shared__ int soff[B_TREES + 1];
    const int t = threadIdx.x, lane = t & 63;
    block_offsets(lens32, soff, t, lane);
    __syncthreads();

    const int b  = blockIdx.x;
    const int s0 = soff[b], s1 = soff[b + 1];
    const int c0 = s0 / CHUNK, c1 = (s1 - 1) / CHUNK;   // chunks intersecting segment b

    float mseg = -INFINITY;
    for (int cc = c0; cc <= c1; ++cc) {
        #pragma unroll
        for (int j = 0; j < 2; ++j) {
            const int sl = 2 * cc + j;
            if (seg_arr[sl] == b) mseg = fmaxf(mseg, m_arr[sl]);
        }
    }
    float zseg = 0.f;
    float4 acc = make_float4(0.f, 0.f, 0.f, 0.f);
    for (int cc = c0; cc <= c1; ++cc) {
        #pragma unroll
        for (int j = 0; j < 2; ++j) {
            const int sl = 2 * cc + j;
            if (seg_arr[sl] == b) {                     // block-uniform
                const float sc = __expf(m_arr[sl] - mseg);
                zseg += sc * z_arr[sl];
                const float4 vv = vec[(size_t)sl * D4 + t];
                acc.x += sc * vv.x; acc.y += sc * vv.y;
                acc.z += sc * vv.z; acc.w += sc * vv.w;
            }
        }
    }
    const float inv = 1.f / zseg;
    acc.x *= inv; acc.y *= inv; acc.z *= inv; acc.w *= inv;
    out[(size_t)b * D4 + t] = acc;
}

extern "C" void kernel_launch(void* const* d_in, const int* in_sizes, int n_in,
                              void* d_out, int out_size, void* d_ws, size_t ws_size,
                              hipStream_t stream) {
    const float* mb   = (const float*)d_in[0];       // [N, 1024]
    const float* ds   = (const float*)d_in[1];       // [64, 1024]
    const float* W    = (const float*)d_in[2];       // [1024, 1024]
    const int*   lens = (const int*)d_in[3];         // [64] int32 (or int64 — autodetected)
    float*       out  = (float*)d_out;               // [64, 1024]

    // workspace layout (~10.3 MB), all 16B-aligned:
    //   v_part [8][64][1024] f32 (2 MB) | m (8 KB) | z (8 KB) | seg (8 KB) | vec (8 MB)
    char*  ws      = (char*)d_ws;
    float* v_part  = (float*)ws;
    float* m_arr   = (float*)(ws + (size_t)VZ * B_TREES * D * 4);
    float* z_arr   = m_arr + NSLOT;
    int*   seg_arr = (int*)(z_arr + NSLOT);
    float* vec     = (float*)((char*)(seg_arr + NSLOT));

    {
        dim3 grid(4, 16, VZ);
        v_kernel<<<grid, 256, 0, stream>>>(ds, W, v_part);
    }

    fused_kernel<<<NCHUNK, 256, 0, stream>>>(
        (const float4*)mb, (const float4*)v_part, lens,
        m_arr, z_arr, seg_arr, (float4*)vec);

    combine_kernel<<<B_TREES, 256, 0, stream>>>(
        lens, m_arr, z_arr, seg_arr, (const float4*)vec, (float4*)out);
}

// Round 5
// 385.733 us; speedup vs baseline: 1.1180x; 1.0356x over previous
//
#include <hip/hip_runtime.h>
#include <math.h>

// Problem constants (fixed by reference)
#define B_TREES 64
#define N_NODES 65536
#define D 1024          // D_MEM == D_HID == 1024
#define D4 (D/4)        // 256 float4 per row

#define CHUNK 64                    // nodes per block (one boundary max: min seg len >= 341)
#define SUB 8                       // nodes per register tile (8 float4/thread = 32 VGPR)
#define NSUB (CHUNK/SUB)            // 8 sub-tiles per chunk
#define NCHUNK (N_NODES/CHUNK)      // 1024 blocks
#define NSLOT (2*NCHUNK)            // 2 slots per chunk (<=2 segments per chunk)
#define VZ 8                        // h-chunks in v_part

// ---- in-block offsets: wave 0 loads lens (int32/int64 autodetect), shfl-scan ----
__device__ __forceinline__ void block_offsets(const int* __restrict__ lens32,
                                              int* __restrict__ soff,
                                              int tid, int lane) {
    if ((tid >> 6) == 0) {
        long long x32 = (long long)lens32[lane];
        long long tot = x32;
        #pragma unroll
        for (int o = 32; o > 0; o >>= 1) tot += __shfl_xor(tot, o, 64);
        int len = (tot == (long long)N_NODES) ? (int)x32
                                              : (int)(((const long long*)lens32)[lane]);
        int scan = len;
        #pragma unroll
        for (int o = 1; o < 64; o <<= 1) {
            int y = __shfl_up(scan, o, 64);
            if (lane >= o) scan += y;
        }
        soff[lane + 1] = scan;
        if (lane == 0) soff[0] = 0;
    }
}

// ---------------- Kernel 1: v_part[z][b][m] = sum_{h in chunk z} ds[b][h]*W[h][m] ----
__global__ __launch_bounds__(256) void v_kernel(const float* __restrict__ ds,
                                                const float* __restrict__ W,
                                                float* __restrict__ v_part) {
    const int m  = blockIdx.x * 256 + threadIdx.x;
    const int b0 = blockIdx.y * 4;
    const int z  = blockIdx.z;
    const int h0 = z * 128;
    float acc[4] = {0.f, 0.f, 0.f, 0.f};
    for (int h = h0; h < h0 + 128; ++h) {
        float wv = W[h * D + m];                 // coalesced across threads
        #pragma unroll
        for (int j = 0; j < 4; ++j)
            acc[j] += ds[(b0 + j) * D + h] * wv; // wave-uniform -> scalar loads
    }
    #pragma unroll
    for (int j = 0; j < 4; ++j)
        v_part[((size_t)(z * B_TREES + b0 + j)) * D + m] = acc[j];
}

// ---------------- Kernel 2: register-resident fused, double-buffered pipeline ----
// Thread t owns d-slice [4t..4t+3]. Two register tiles (A,B): tile st+1's 8
// coalesced loads issue at the TOP of the body, so they fly across the
// reduce+barrier+accum window of tile st. Score reduce = packed butterfly
// (10 shfl + selects) + tiny double-buffered LDS combine (1 barrier/sub-tile).
struct FusedState {
    float  m0, z0, m1, z1;
    float4 a0, a1;
};

__device__ __forceinline__ void fused_body(
    const float4* __restrict__ mb, float4 (&CUR)[SUB], float4 (&NXT)[SUB],
    int ST, int n0, int cutg, const float4& vA, const float4& vB,
    int tid, int wave, int lane, float (*red)[4][SUB], FusedState& S)
{
    const int nb = n0 + ST * SUB;

    // ---- issue next tile's loads first; they retire under this tile's work
    if (ST + 1 < NSUB) {
        const int nb2 = nb + SUB;
        #pragma unroll
        for (int k = 0; k < SUB; ++k)
            NXT[k] = mb[(size_t)(nb2 + k) * D4 + tid];
    }

    // ---- per-thread partial dots (block-uniform branch on the cut)
    float p[SUB];
    if (nb + SUB <= cutg) {
        #pragma unroll
        for (int k = 0; k < SUB; ++k)
            p[k] = CUR[k].x*vA.x + CUR[k].y*vA.y + CUR[k].z*vA.z + CUR[k].w*vA.w;
    } else if (nb >= cutg) {
        #pragma unroll
        for (int k = 0; k < SUB; ++k)
            p[k] = CUR[k].x*vB.x + CUR[k].y*vB.y + CUR[k].z*vB.z + CUR[k].w*vB.w;
    } else {
        #pragma unroll
        for (int k = 0; k < SUB; ++k) {
            const float4 vk = (nb + k < cutg) ? vA : vB;
            p[k] = CUR[k].x*vk.x + CUR[k].y*vk.y + CUR[k].z*vk.z + CUR[k].w*vk.w;
        }
    }

    // ---- packed butterfly: fold 8 values into 1 reg, k encoded in lane&7
    float r01, r23, r45, r67, q0, q1, r;
    {
        const bool h1 = (lane & 1) != 0;
        float keep, send;
        keep = h1 ? p[1] : p[0]; send = h1 ? p[0] : p[1];
        r01 = keep + __shfl_xor(send, 1, 64);
        keep = h1 ? p[3] : p[2]; send = h1 ? p[2] : p[3];
        r23 = keep + __shfl_xor(send, 1, 64);
        keep = h1 ? p[5] : p[4]; send = h1 ? p[4] : p[5];
        r45 = keep + __shfl_xor(send, 1, 64);
        keep = h1 ? p[7] : p[6]; send = h1 ? p[6] : p[7];
        r67 = keep + __shfl_xor(send, 1, 64);
    }
    {
        const bool h2 = (lane & 2) != 0;
        float keep, send;
        keep = h2 ? r23 : r01; send = h2 ? r01 : r23;
        q0 = keep + __shfl_xor(send, 2, 64);
        keep = h2 ? r67 : r45; send = h2 ? r45 : r67;
        q1 = keep + __shfl_xor(send, 2, 64);
    }
    {
        const bool h4 = (lane & 4) != 0;
        float keep = h4 ? q1 : q0, send = h4 ? q0 : q1;
        r = keep + __shfl_xor(send, 4, 64);
    }
    r += __shfl_xor(r, 8, 64);
    r += __shfl_xor(r, 16, 64);
    r += __shfl_xor(r, 32, 64);
    // lane l now holds this wave's sum of p[l&7]

    const int par = ST & 1;
    if (lane < 8) red[par][wave][lane] = r;
    __syncthreads();
    float s_[SUB];
    #pragma unroll
    for (int k = 0; k < SUB; ++k)
        s_[k] = red[par][0][k] + red[par][1][k] + red[par][2][k] + red[par][3][k];

    // ---- online-softmax weighted accumulate from registers (block-uniform)
    #pragma unroll
    for (int k = 0; k < SUB; ++k) {
        const float sc_ = s_[k];
        if (nb + k < cutg) {
            if (sc_ > S.m0) {
                const float rr = __expf(S.m0 - sc_);   // exp(-inf)=0 handles init
                S.z0 *= rr; S.a0.x *= rr; S.a0.y *= rr; S.a0.z *= rr; S.a0.w *= rr;
                S.m0 = sc_;
            }
            const float w = __expf(sc_ - S.m0);
            S.z0 += w;
            S.a0.x += w * CUR[k].x; S.a0.y += w * CUR[k].y;
            S.a0.z += w * CUR[k].z; S.a0.w += w * CUR[k].w;
        } else {
            if (sc_ > S.m1) {
                const float rr = __expf(S.m1 - sc_);
                S.z1 *= rr; S.a1.x *= rr; S.a1.y *= rr; S.a1.z *= rr; S.a1.w *= rr;
                S.m1 = sc_;
            }
            const float w = __expf(sc_ - S.m1);
            S.z1 += w;
            S.a1.x += w * CUR[k].x; S.a1.y += w * CUR[k].y;
            S.a1.z += w * CUR[k].z; S.a1.w += w * CUR[k].w;
        }
    }
    // parity double-buffer on red[] separates this tile's reads from the
    // write at ST+2 by the ST+1 barrier; no trailing barrier needed.
}

__global__ __launch_bounds__(256, 3) void fused_kernel(
    const float4* __restrict__ mb, const float4* __restrict__ v_part,
    const int* __restrict__ lens32,
    float* __restrict__ m_arr, float* __restrict__ z_arr,
    int* __restrict__ seg_arr, float4* __restrict__ vec)
{
    __shared__ float red[2][4][SUB];     // [parity][wave][node] wave sums
    __shared__ int   soff[B_TREES + 1];

    const int tid  = threadIdx.x;
    const int wave = tid >> 6;
    const int lane = tid & 63;
    const int c    = blockIdx.x;
    const int n0   = c * CHUNK;

    // ---- prologue: issue tile-0 loads first (independent of the scan below)
    float4 bufA[SUB], bufB[SUB];
    #pragma unroll
    for (int k = 0; k < SUB; ++k)
        bufA[k] = mb[(size_t)(n0 + k) * D4 + tid];

    block_offsets(lens32, soff, tid, lane);
    __syncthreads();

    // segment geometry (block-uniform; soff reads are LDS broadcasts)
    int lo = 0, hi = B_TREES - 1;
    while (lo < hi) { int mid = (lo + hi + 1) >> 1; if (soff[mid] <= n0) lo = mid; else hi = mid - 1; }
    const int sa   = lo;
    const int nxt  = soff[sa + 1];
    const int cutg = (nxt < n0 + CHUNK) ? nxt : 0x7fffffff;
    const bool two = (cutg != 0x7fffffff);

    // this thread's v-slice(s); loads overlap tile-0 flight
    float4 vA = make_float4(0.f, 0.f, 0.f, 0.f);
    #pragma unroll
    for (int z = 0; z < VZ; ++z) {
        const float4 t4 = v_part[(size_t)(z * B_TREES + sa) * D4 + tid];
        vA.x += t4.x; vA.y += t4.y; vA.z += t4.z; vA.w += t4.w;
    }
    float4 vB = vA;
    if (two) {
        vB = make_float4(0.f, 0.f, 0.f, 0.f);
        #pragma unroll
        for (int z = 0; z < VZ; ++z) {
            const float4 t4 = v_part[(size_t)(z * B_TREES + sa + 1) * D4 + tid];
            vB.x += t4.x; vB.y += t4.y; vB.z += t4.z; vB.w += t4.w;
        }
    }

    FusedState S;
    S.m0 = -INFINITY; S.z0 = 0.f; S.m1 = -INFINITY; S.z1 = 0.f;
    S.a0 = make_float4(0.f, 0.f, 0.f, 0.f);
    S.a1 = make_float4(0.f, 0.f, 0.f, 0.f);

    #pragma unroll
    for (int st = 0; st < NSUB; st += 2) {
        fused_body(mb, bufA, bufB, st,     n0, cutg, vA, vB, tid, wave, lane, red, S);
        fused_body(mb, bufB, bufA, st + 1, n0, cutg, vA, vB, tid, wave, lane, red, S);
    }

    // ---- emit chunk partials (every slot's segid is written every launch)
    const int slot0 = 2 * c, slot1 = 2 * c + 1;
    vec[(size_t)slot0 * D4 + tid] = S.a0;
    if (tid == 0) { m_arr[slot0] = S.m0; z_arr[slot0] = S.z0; seg_arr[slot0] = sa; }
    if (two) {
        vec[(size_t)slot1 * D4 + tid] = S.a1;
        if (tid == 0) { m_arr[slot1] = S.m1; z_arr[slot1] = S.z1; seg_arr[slot1] = sa + 1; }
    } else if (tid == 0) {
        seg_arr[slot1] = -1;
    }
}

// ---------------- Kernel 3: combine chunk partials per segment ----------------
__global__ __launch_bounds__(256) void combine_kernel(
    const int* __restrict__ lens32, const float* __restrict__ m_arr,
    const float* __restrict__ z_arr, const int* __restrict__ seg_arr,
    const float4* __restrict__ vec, float4* __restrict__ out)
{
    __shared__ int soff[B_TREES + 1];
    const int t = threadIdx.x, lane = t & 63;
    block_offsets(lens32, soff, t, lane);
    __syncthreads();

    const int b  = blockIdx.x;
    const int s0 = soff[b], s1 = soff[b + 1];
    const int c0 = s0 / CHUNK, c1 = (s1 - 1) / CHUNK;   // chunks intersecting segment b

    float mseg = -INFINITY;
    for (int cc = c0; cc <= c1; ++cc) {
        #pragma unroll
        for (int j = 0; j < 2; ++j) {
            const int sl = 2 * cc + j;
            if (seg_arr[sl] == b) mseg = fmaxf(mseg, m_arr[sl]);
        }
    }
    float zseg = 0.f;
    float4 acc = make_float4(0.f, 0.f, 0.f, 0.f);
    for (int cc = c0; cc <= c1; ++cc) {
        #pragma unroll
        for (int j = 0; j < 2; ++j) {
            const int sl = 2 * cc + j;
            if (seg_arr[sl] == b) {                     // block-uniform
                const float sc = __expf(m_arr[sl] - mseg);
                zseg += sc * z_arr[sl];
                const float4 vv = vec[(size_t)sl * D4 + t];
                acc.x += sc * vv.x; acc.y += sc * vv.y;
                acc.z += sc * vv.z; acc.w += sc * vv.w;
            }
        }
    }
    const float inv = 1.f / zseg;
    acc.x *= inv; acc.y *= inv; acc.z *= inv; acc.w *= inv;
    out[(size_t)b * D4 + t] = acc;
}

extern "C" void kernel_launch(void* const* d_in, const int* in_sizes, int n_in,
                              void* d_out, int out_size, void* d_ws, size_t ws_size,
                              hipStream_t stream) {
    const float* mb   = (const float*)d_in[0];       // [N, 1024]
    const float* ds   = (const float*)d_in[1];       // [64, 1024]
    const float* W    = (const float*)d_in[2];       // [1024, 1024]
    const int*   lens = (const int*)d_in[3];         // [64] int32 (or int64 — autodetected)
    float*       out  = (float*)d_out;               // [64, 1024]

    // workspace layout (~10.3 MB), all 16B-aligned:
    //   v_part [8][64][1024] f32 (2 MB) | m (8 KB) | z (8 KB) | seg (8 KB) | vec (8 MB)
    char*  ws      = (char*)d_ws;
    float* v_part  = (float*)ws;
    float* m_arr   = (float*)(ws + (size_t)VZ * B_TREES * D * 4);
    float* z_arr   = m_arr + NSLOT;
    int*   seg_arr = (int*)(z_arr + NSLOT);
    float* vec     = (float*)((char*)(seg_arr + NSLOT));

    {
        dim3 grid(4, 16, VZ);
        v_kernel<<<grid, 256, 0, stream>>>(ds, W, v_part);
    }

    fused_kernel<<<NCHUNK, 256, 0, stream>>>(
        (const float4*)mb, (const float4*)v_part, lens,
        m_arr, z_arr, seg_arr, (float4*)vec);

    combine_kernel<<<B_TREES, 256, 0, stream>>>(
        lens, m_arr, z_arr, seg_arr, (const float4*)vec, (float4*)out);
}